// Round 9
// baseline (200.970 us; speedup 1.0000x reference)
//
#include <hip/hip_runtime.h>
#include <hip/hip_bf16.h>

typedef unsigned short u16;

#define BATCH 8
#define CIN 512
#define COUT 512
#define SDIM 512
#define RES 64
#define PIX (RES * RES)          // 4096
#define PPIX 4356                // padded 66x66
#define PANEL_E 139392           // PPIX*32 elems per padded B panel

__device__ __constant__ static const float kAffScale  = 0.04419417382415922f;   // 1/sqrt(512)
__device__ __constant__ static const float kConvScale = 0.014731391274719742f;  // 1/sqrt(512*9)
__device__ __constant__ static const float kGain      = 1.4142135623730951f;    // sqrt(2)

typedef __bf16 bf16x8 __attribute__((ext_vector_type(8)));
typedef float  f32x4  __attribute__((ext_vector_type(4)));

// ---------------------------------------------------------------------------
// Kernel 1: style[b][c] = (w[b] . affine_w[c]) * AFF_SCALE + affine_b[c]
// ---------------------------------------------------------------------------
__global__ void style_k(const float* __restrict__ w, const float* __restrict__ aw,
                        const float* __restrict__ ab, float* __restrict__ style) {
  int tid = blockIdx.x * 256 + threadIdx.x;      // 0..4095
  int b = tid >> 9, c = tid & 511;
  const float* wp = w + b * SDIM;
  const float* ap = aw + c * SDIM;
  float s = 0.0f;
  for (int k = 0; k < SDIM; ++k) s += wp[k] * ap[k];
  style[tid] = s * kAffScale + ab[c];
}

// ---------------------------------------------------------------------------
// Kernel 2: cw2[o][i] = sum_t conv_w[o][i][t]^2
// ---------------------------------------------------------------------------
__global__ void cw2_k(const float* __restrict__ cw, float* __restrict__ cw2) {
  int tid = blockIdx.x * 256 + threadIdx.x;      // o*512+i
  const float* p = cw + tid * 9;
  float s = 0.0f;
  #pragma unroll
  for (int t = 0; t < 9; ++t) { float v = p[t]; s += v * v; }
  cw2[tid] = s;
}

// ---------------------------------------------------------------------------
// Kernel 3: fac[b][o] = CONV_SCALE * rsqrt(CONV_SCALE^2 * sum_i style^2*cw2 + 1e-8)
// ---------------------------------------------------------------------------
__global__ void fac_k(const float* __restrict__ style, const float* __restrict__ cw2,
                      float* __restrict__ fac) {
  int wid  = blockIdx.x * 4 + (threadIdx.x >> 6); // 0..4095
  int lane = threadIdx.x & 63;
  int b = wid >> 9, o = wid & 511;
  const float* st = style + b * CIN;
  const float* c2 = cw2 + o * CIN;
  float s = 0.0f;
  for (int i = lane; i < CIN; i += 64) { float sv = st[i]; s += sv * sv * c2[i]; }
  #pragma unroll
  for (int off = 32; off; off >>= 1) s += __shfl_xor(s, off);
  if (lane == 0) {
    float d = rsqrtf(s * kConvScale * kConvScale + 1e-8f);
    fac[wid] = d * kConvScale;
  }
}

// ---------------------------------------------------------------------------
// Kernel 4: wbt[(tap*16+sl)][o][j] = bf16(conv_w[o][sl*32+j][tap])
// ---------------------------------------------------------------------------
__global__ void wcast_k(const float* __restrict__ cw, u16* __restrict__ wbt) {
  int tid = blockIdx.x * 256 + threadIdx.x;      // o*512 + i
  int o = tid >> 9, i = tid & 511;
  const float* p = cw + tid * 9;
  #pragma unroll
  for (int t = 0; t < 9; ++t) {
    __hip_bfloat16 h = __float2bfloat16(p[t]);
    wbt[((size_t)(t * 16 + (i >> 5)) * 512 + o) * 32 + (i & 31)] = *(u16*)&h;
  }
}

// ---------------------------------------------------------------------------
// Kernel 5a: zero the 1-pixel borders of all 128 padded B panels
// ---------------------------------------------------------------------------
__global__ void bz_k(u16* __restrict__ xst) {
  int idx = blockIdx.x * 256 + threadIdx.x;      // panel*4356 + pix
  if (idx >= 128 * PPIX) return;
  int pan = idx / PPIX, pix = idx - pan * PPIX;
  int h = pix / 66, w = pix - h * 66;
  if (h == 0 || h == 65 || w == 0 || w == 65) {
    u16* p = xst + (size_t)pan * PANEL_E + (size_t)pix * 32;
    int4 z = make_int4(0, 0, 0, 0);
    ((int4*)p)[0] = z; ((int4*)p)[1] = z; ((int4*)p)[2] = z; ((int4*)p)[3] = z;
  }
}

// ---------------------------------------------------------------------------
// Kernel 5b: xst[(b*16+sl)][(h+1)*66+(w+1)][j] = bf16(x[b][sl*32+j][h*64+w]*style)
// ---------------------------------------------------------------------------
__global__ void modx_k(const float* __restrict__ x, const float* __restrict__ style,
                       u16* __restrict__ xst) {
  __shared__ float t[64][65];
  int b  = blockIdx.z;
  int it = blockIdx.y * 64;                      // cin tile base
  int pt = blockIdx.x * 64;                      // pixel tile base
  int tp = threadIdx.x & 63;
  int tr = threadIdx.x >> 6;                     // 0..3
  for (int r = tr; r < 64; r += 4) {
    int i = it + r;
    t[r][tp] = x[(b * CIN + i) * PIX + pt + tp] * style[b * CIN + i];
  }
  __syncthreads();
  int i = it + tp;
  size_t pbase = (size_t)(b * 16 + (i >> 5)) * PANEL_E + (i & 31);
  for (int r = tr; r < 64; r += 4) {
    int pix = pt + r, h = pix >> 6, w = pix & 63;
    __hip_bfloat16 hh = __float2bfloat16(t[tp][r]);
    xst[pbase + (size_t)((h + 1) * 66 + (w + 1)) * 32] = *(u16*)&hh;
  }
}

// ---------------------------------------------------------------------------
// Kernel 6: implicit-GEMM conv. B operand: direct global->VGPR (coalesced
// b128 frags from padded NHWC-32 panels, issued 2 halves ahead into a 3-set
// register ring q0/q1/q2). A: LDS ring-3 (96 KB), 8 ds_read_b128 per half.
// Per half (32 MFMA): reads 4+4 pinned, stage A quantum, issue 4 B-loads,
// barrier, lgkm(4), 16 MFMA, lgkm(0), 16 MFMA, vmcnt(6), barrier.
// vmcnt never 0. cin-block-major K-order (cb 0..7, tap 0..8, kh 0..1).
// 8 waves (2Mx4N), wave out 128x64, BM=BN=256.
// ---------------------------------------------------------------------------
__launch_bounds__(512, 2)
__global__ void gemm_k(const u16* __restrict__ wbt, const u16* __restrict__ xst,
                       const float* __restrict__ fac, const float* __restrict__ noise,
                       const float* __restrict__ nscale_p, const float* __restrict__ bias,
                       float* __restrict__ y) {
  __shared__ __align__(16) u16 Ab[49152];        // A ring-3 x [kh][256 rows][32] = 96 KB

  const int tid = threadIdx.x;
  const int bid = blockIdx.x;                    // 0..255
  const int swz = (bid & 7) * 32 + (bid >> 3);   // XCD-chunked (256 % 8 == 0)
  const int mt = swz >> 7;                       // 0..1   cout tile
  const int nt = swz & 127;                      // 0..127 pixel tile
  const int b  = nt >> 4;                        // image
  const int pimg  = (nt & 15) * 256;             // pixel base within image
  const int hbase = pimg >> 6;                   // image row base (0,4,..,60)

  const int lane = tid & 63;
  const int wv = tid >> 6;                       // 0..7
  const int wm = wv >> 2;                        // 0..1  (128 out-rows)
  const int wn = wv & 3;                         // 0..3  (64 out-cols = image row hbase+wn)
  const int l15 = lane & 15, l4 = lane >> 4;

  // A-read element addresses (per-thread constants), 8 m-fragments
  int aElem[8];
  #pragma unroll
  for (int mi = 0; mi < 8; ++mi) {
    int arow = wm * 128 + mi * 16 + l15;
    aElem[mi] = arow * 32 + ((l4 ^ ((arow >> 1) & 3)) << 3);
  }

  // A staging per-thread constants
  const int sgE = ((tid & 3) ^ ((tid >> 3) & 3)) << 3;
  int aoffE[2];
  #pragma unroll
  for (int p = 0; p < 2; ++p)
    aoffE[p] = (mt * 256 + ((p * 512 + tid) >> 2)) * 32 + sgE;

  // B per-lane constant offset (elems) within a padded panel (center pixel)
  const int pB0 = ((hbase + wn + 1) * 66 + l15 + 1) * 32 + l4 * 8;

  auto stA = [&](int panel, int ring, int khS) {
    const u16* pan = wbt + ((size_t)panel << 14);
    #pragma unroll
    for (int p = 0; p < 2; ++p) {
      __builtin_amdgcn_global_load_lds(
          (const __attribute__((address_space(1))) void*)(pan + aoffE[p]),
          (__attribute__((address_space(3))) void*)(&Ab[ring * 16384 + khS * 8192 + (p * 512 + tid) * 8]),
          16, 0, 0);
    }
  };

  f32x4 acc[8][4];
  #pragma unroll
  for (int i = 0; i < 8; ++i)
    #pragma unroll
    for (int j = 0; j < 4; ++j) acc[i][j] = (f32x4){0.f, 0.f, 0.f, 0.f};

  bf16x8 q0[4], q1[4], q2[4];                    // B register ring (static idx)

#define BISSUE(SN, TAPB, CBB, KHB) {                                           \
    const u16* pb_ = xst + (size_t)(b * 16 + (CBB) * 2 + (KHB)) * PANEL_E      \
        + ((((TAPB) / 3) - 1) * 66 + ((TAPB) % 3) - 1) * 32 + pB0;             \
    _Pragma("unroll") for (int ni = 0; ni < 4; ++ni)                           \
      SN[ni] = *(const bf16x8*)(pb_ + ni * 512);                               \
  }

#define MFMA16(AF, BQ, MOFF)                                                   \
    _Pragma("unroll") for (int j = 0; j < 4; ++j)                              \
      _Pragma("unroll") for (int ni = 0; ni < 4; ++ni)                         \
        acc[(MOFF) + j][ni] = __builtin_amdgcn_mfma_f32_16x16x32_bf16(         \
            AF[j], BQ[ni], acc[(MOFF) + j][ni], 0, 0, 0);

  // Prologue: A kt0 (ring0) + kt1 (ring1) fully staged; B halves 0,1 issued.
  {
    const int cbw0 = 0;
    stA(0, 0, 0); stA(1, 0, 1);                  // tap0 cb0 kh0/kh1 -> ring0
    stA(16, 1, 0); stA(17, 1, 1);                // tap1 cb0 kh0/kh1 -> ring1
    BISSUE(q0, 0, cbw0, 0)                       // B for half 0 (tap0 kh0)
    BISSUE(q1, 0, cbw0, 1)                       // B for half 1 (tap0 kh1)
  }
  asm volatile("s_waitcnt vmcnt(4)" ::: "memory"); // kt0 + B(h0) landed
  __builtin_amdgcn_s_barrier();

  // One half: consume SC (B regs), read af from ring TAP%3, stage A(kt+2)
  // kh-slice, issue B for half+2 into SN. 2 barriers, counted waits only.
#define HALF(TAP, KH, SC, SN, TAPB, CBB) {                                     \
    constexpr int rr_ = (TAP) % 3;                                             \
    constexpr int rw_ = ((TAP) + 2) % 3;                                       \
    constexpr int tp2_ = ((TAP) + 2) % 9;                                      \
    const int cbS_ = ((TAP) < 7) ? cb : cbw;                                   \
    bf16x8 af03[4], af47[4];                                                   \
    _Pragma("unroll") for (int j = 0; j < 4; ++j)                              \
      af03[j] = *(const bf16x8*)&Ab[rr_ * 16384 + (KH) * 8192 + aElem[j]];     \
    __builtin_amdgcn_sched_barrier(0);  /* af03 = oldest 4 lgkm */             \
    _Pragma("unroll") for (int j = 0; j < 4; ++j)                              \
      af47[j] = *(const bf16x8*)&Ab[rr_ * 16384 + (KH) * 8192 + aElem[4 + j]]; \
    stA(tp2_ * 16 + cbS_ * 2 + (KH), rw_, (KH));                               \
    BISSUE(SN, TAPB, CBB, KH)                                                  \
    __builtin_amdgcn_sched_barrier(0);  /* keep all issues above barrier */    \
    __builtin_amdgcn_s_barrier();                                              \
    asm volatile("s_waitcnt lgkmcnt(4)" ::: "memory");                         \
    __builtin_amdgcn_sched_barrier(0);                                         \
    __builtin_amdgcn_s_setprio(1);                                             \
    MFMA16(af03, SC, 0)                                                        \
    __builtin_amdgcn_s_setprio(0);                                             \
    asm volatile("s_waitcnt lgkmcnt(0)" ::: "memory");                         \
    __builtin_amdgcn_sched_barrier(0);                                         \
    __builtin_amdgcn_s_setprio(1);                                             \
    MFMA16(af47, SC, 4)                                                        \
    __builtin_amdgcn_s_setprio(0);                                             \
    asm volatile("s_waitcnt vmcnt(6)" ::: "memory");                           \
    __builtin_amdgcn_s_barrier();                                              \
  }

  for (int cb = 0; cb < 8; ++cb) {
    const int cbw = (cb == 7) ? 0 : cb + 1;
    HALF(0, 0, q0, q2, 1, cb)  HALF(0, 1, q1, q0, 1, cb)
    HALF(1, 0, q2, q1, 2, cb)  HALF(1, 1, q0, q2, 2, cb)
    HALF(2, 0, q1, q0, 3, cb)  HALF(2, 1, q2, q1, 3, cb)
    HALF(3, 0, q0, q2, 4, cb)  HALF(3, 1, q1, q0, 4, cb)
    HALF(4, 0, q2, q1, 5, cb)  HALF(4, 1, q0, q2, 5, cb)
    HALF(5, 0, q1, q0, 6, cb)  HALF(5, 1, q2, q1, 6, cb)
    HALF(6, 0, q0, q2, 7, cb)  HALF(6, 1, q1, q0, 7, cb)
    HALF(7, 0, q2, q1, 8, cb)  HALF(7, 1, q0, q2, 8, cb)
    HALF(8, 0, q1, q0, 0, cbw) HALF(8, 1, q2, q1, 0, cbw)
  }
#undef HALF
#undef MFMA16
#undef BISSUE

  // Epilogue: y = lrelu(acc*fac + noise*nscale + bias) * sqrt(2)
  const float ns = nscale_p[0];
  float nz[4];
  #pragma unroll
  for (int ni = 0; ni < 4; ++ni) {
    int pix = pimg + wn * 64 + ni * 16 + l15;
    nz[ni] = noise[b * PIX + pix] * ns;
  }
  #pragma unroll
  for (int mi = 0; mi < 8; ++mi) {
    int o = mt * 256 + wm * 128 + mi * 16 + l4 * 4;
    f32x4 fv = *(const f32x4*)&fac[b * COUT + o];
    f32x4 bv = *(const f32x4*)&bias[o];
    #pragma unroll
    for (int r = 0; r < 4; ++r) {
      float* yp = y + (size_t)(b * COUT + o + r) * PIX + pimg + wn * 64 + l15;
      #pragma unroll
      for (int ni = 0; ni < 4; ++ni) {
        float v = acc[mi][ni][r] * fv[r] + nz[ni] + bv[r];
        v = (v > 0.0f ? v : 0.2f * v) * kGain;
        yp[ni * 16] = v;
      }
    }
  }
}

// ---------------------------------------------------------------------------
extern "C" void kernel_launch(void* const* d_in, const int* in_sizes, int n_in,
                              void* d_out, int out_size, void* d_ws, size_t ws_size,
                              hipStream_t stream) {
  const float* x      = (const float*)d_in[0];
  const float* w      = (const float*)d_in[1];
  const float* noise  = (const float*)d_in[2];
  const float* aff_w  = (const float*)d_in[3];
  const float* aff_b  = (const float*)d_in[4];
  const float* conv_w = (const float*)d_in[5];
  const float* nscale = (const float*)d_in[6];
  const float* bias   = (const float*)d_in[7];
  float* y = (float*)d_out;

  char* ws = (char*)d_ws;
  float* style = (float*)(ws);                          // 16 KB
  float* fac   = (float*)(ws + 16384);                  // 16 KB
  float* cw2   = (float*)(ws + 32768);                  // 1 MB
  u16*   wbt   = (u16*)(ws + 1081600);                  // 4.5 MB panels
  u16*   xst   = (u16*)(ws + 5800192);                  // 128 padded panels, 35.7 MB

  style_k<<<16, 256, 0, stream>>>(w, aff_w, aff_b, style);
  cw2_k<<<1024, 256, 0, stream>>>(conv_w, cw2);
  fac_k<<<1024, 256, 0, stream>>>(style, cw2, fac);
  wcast_k<<<1024, 256, 0, stream>>>(conv_w, wbt);
  bz_k<<<(128 * PPIX + 255) / 256, 256, 0, stream>>>(xst);
  modx_k<<<dim3(64, 8, 8), 256, 0, stream>>>(x, style, xst);
  gemm_k<<<256, 512, 0, stream>>>(wbt, xst, fac, noise, nscale, bias, y);
}